// Round 14
// baseline (389.506 us; speedup 1.0000x reference)
//
#include <hip/hip_runtime.h>
#include <hip/hip_bf16.h>
#include <stdint.h>

// RWKV4 time-mix for B=4, T=2048, H=2048 on gfx950.
#define B_ 4
#define T_ 2048
#define H_ 2048
#define BT_ (B_ * T_)
#define BH_ (B_ * H_)
#define CH_ 32              // number of time chunks for the WKV scan
#define CL_ (T_ / CH_)      // chunk length = 64
#define NKT_ (H_ / 64)      // 32 K-tiles of BK=64 for the GEMM

typedef __bf16 bf16x8 __attribute__((ext_vector_type(8)));
typedef float f32x4 __attribute__((ext_vector_type(4)));

// async global->LDS, 16B per lane. LDS dest is wave-uniform base + lane*16.
__device__ inline void async16(const void* g, void* l) {
  __builtin_amdgcn_global_load_lds(
      (__attribute__((address_space(1))) uint32_t*)(void*)(uintptr_t)g,
      (__attribute__((address_space(3))) uint32_t*)l,
      16, 0, 0);
}

// ------------------------------------------- f32 -> bf16 (all 4 weights, 1 launch)
__global__ __launch_bounds__(256) void cvt_bf16_kernel(
    const float* __restrict__ w0, const float* __restrict__ w1,
    const float* __restrict__ w2, const float* __restrict__ w3,
    __bf16* __restrict__ dst /* 4 contiguous H*H blocks */) {
  const float* srcs[4] = {w0, w1, w2, w3};
  const float* src = srcs[blockIdx.y];
  __bf16* d = dst + (size_t)blockIdx.y * H_ * H_;
  int i = (blockIdx.x * 256 + threadIdx.x) * 8;
  const float4* s4 = (const float4*)(src + i);
  float4 a = s4[0], b = s4[1];
  bf16x8 o;
  o[0] = (__bf16)a.x; o[1] = (__bf16)a.y; o[2] = (__bf16)a.z; o[3] = (__bf16)a.w;
  o[4] = (__bf16)b.x; o[5] = (__bf16)b.y; o[6] = (__bf16)b.z; o[7] = (__bf16)b.w;
  *(bf16x8*)(d + i) = o;
}

// ------------------------------------------------- LayerNorm + token-shift mix
__global__ __launch_bounds__(256) void ln_mix_kernel(
    const float* __restrict__ h, const float* __restrict__ lnw,
    const float* __restrict__ lnb, const float* __restrict__ mk,
    const float* __restrict__ mv, const float* __restrict__ mr,
    __bf16* __restrict__ xk, __bf16* __restrict__ xv, __bf16* __restrict__ xr,
    float* __restrict__ xlast) {
  const int row = blockIdx.x;          // b*T + t
  const int t = row & (T_ - 1);
  const int tid = threadIdx.x;
  const bool hasprev = (t != 0);

  const float4* cr = (const float4*)(h + (size_t)row * H_);
  float4 c0 = cr[tid * 2 + 0], c1 = cr[tid * 2 + 1];
  float4 p0 = {0.f, 0.f, 0.f, 0.f}, p1 = {0.f, 0.f, 0.f, 0.f};
  if (hasprev) {
    const float4* pr = (const float4*)(h + (size_t)(row - 1) * H_);
    p0 = pr[tid * 2 + 0]; p1 = pr[tid * 2 + 1];
  }
  float4 red;
  red.x = c0.x + c0.y + c0.z + c0.w + c1.x + c1.y + c1.z + c1.w;
  red.y = c0.x * c0.x + c0.y * c0.y + c0.z * c0.z + c0.w * c0.w +
          c1.x * c1.x + c1.y * c1.y + c1.z * c1.z + c1.w * c1.w;
  red.z = p0.x + p0.y + p0.z + p0.w + p1.x + p1.y + p1.z + p1.w;
  red.w = p0.x * p0.x + p0.y * p0.y + p0.z * p0.z + p0.w * p0.w +
          p1.x * p1.x + p1.y * p1.y + p1.z * p1.z + p1.w * p1.w;
  #pragma unroll
  for (int off = 32; off; off >>= 1) {
    red.x += __shfl_down(red.x, off);
    red.y += __shfl_down(red.y, off);
    red.z += __shfl_down(red.z, off);
    red.w += __shfl_down(red.w, off);
  }
  __shared__ float4 rbuf_[4];
  const int lane = tid & 63, wid = tid >> 6;
  if (lane == 0) rbuf_[wid] = red;
  __syncthreads();
  float4 tot;
  tot.x = rbuf_[0].x + rbuf_[1].x + rbuf_[2].x + rbuf_[3].x;
  tot.y = rbuf_[0].y + rbuf_[1].y + rbuf_[2].y + rbuf_[3].y;
  tot.z = rbuf_[0].z + rbuf_[1].z + rbuf_[2].z + rbuf_[3].z;
  tot.w = rbuf_[0].w + rbuf_[1].w + rbuf_[2].w + rbuf_[3].w;

  const float inv = 1.0f / (float)H_;
  float mu = tot.x * inv;
  float rstd = rsqrtf(fmaxf(tot.y * inv - mu * mu, 0.f) + 1e-5f);
  float mup = tot.z * inv;
  float rstdp = rsqrtf(fmaxf(tot.w * inv - mup * mup, 0.f) + 1e-5f);

  float xc[8] = {c0.x, c0.y, c0.z, c0.w, c1.x, c1.y, c1.z, c1.w};
  float xp[8] = {p0.x, p0.y, p0.z, p0.w, p1.x, p1.y, p1.z, p1.w};
  const float4* W4 = (const float4*)lnw;
  const float4* Bv4 = (const float4*)lnb;
  const float4* MK4 = (const float4*)mk;
  const float4* MV4 = (const float4*)mv;
  const float4* MR4 = (const float4*)mr;
  float4 w0 = W4[tid * 2], w1 = W4[tid * 2 + 1];
  float4 b0 = Bv4[tid * 2], b1 = Bv4[tid * 2 + 1];
  float4 k0 = MK4[tid * 2], k1 = MK4[tid * 2 + 1];
  float4 v0 = MV4[tid * 2], v1 = MV4[tid * 2 + 1];
  float4 r0 = MR4[tid * 2], r1 = MR4[tid * 2 + 1];
  float wa[8] = {w0.x, w0.y, w0.z, w0.w, w1.x, w1.y, w1.z, w1.w};
  float ba[8] = {b0.x, b0.y, b0.z, b0.w, b1.x, b1.y, b1.z, b1.w};
  float ka[8] = {k0.x, k0.y, k0.z, k0.w, k1.x, k1.y, k1.z, k1.w};
  float va[8] = {v0.x, v0.y, v0.z, v0.w, v1.x, v1.y, v1.z, v1.w};
  float ra[8] = {r0.x, r0.y, r0.z, r0.w, r1.x, r1.y, r1.z, r1.w};

  bf16x8 ok_, ov_, or_;
  float xls[8];
  #pragma unroll
  for (int e = 0; e < 8; e++) {
    float x = (xc[e] - mu) * rstd * wa[e] + ba[e];
    float sx = hasprev ? (xp[e] - mup) * rstdp * wa[e] + ba[e] : 0.f;
    ok_[e] = (__bf16)(sx + ka[e] * (x - sx));
    ov_[e] = (__bf16)(sx + va[e] * (x - sx));
    or_[e] = (__bf16)(sx + ra[e] * (x - sx));
    xls[e] = x;
  }
  size_t obase = (size_t)row * H_ + tid * 8;
  *(bf16x8*)(xk + obase) = ok_;
  *(bf16x8*)(xv + obase) = ov_;
  *(bf16x8*)(xr + obase) = or_;
  if (t == T_ - 1) {
    float* dst = xlast + (size_t)(row >> 11) * H_ + tid * 8;
    #pragma unroll
    for (int e = 0; e < 8; e++) dst[e] = xls[e];
  }
}

// ----------------------- fused k/v/r bf16 NT GEMM, 128^2 tile, BK=64
// R10 map (per-z XCD swizzle, bm-first chunk) + R12 setprio (T5).
// Verified: ~197 us for 3 GEMM-equivalents, MfmaUtil 48%.
__global__ __launch_bounds__(256, 2) void gemm_kvr(
    const __bf16* __restrict__ A0, const __bf16* __restrict__ A1,
    const __bf16* __restrict__ A2, const __bf16* __restrict__ Wb,
    __bf16* __restrict__ o0, __bf16* __restrict__ o1, __bf16* __restrict__ o2) {
  __shared__ __align__(16) char ring[2][32768];   // [buf][A 16K | B 16K]

  // z-slab, then per-z bijective XCD swizzle with bm-first chunk order.
  const int wgid = blockIdx.x;          // 0..3071
  const int z = wgid >> 10;             // 0..2
  const int g = wgid & 1023;
  const int x = g & 7;                  // XCD
  const int i = g >> 3;                 // 0..127 within XCD chunk
  const int bm = x * 8 + (i & 7);       // 0..63  (M/128), bm-first
  const int bn = i >> 3;                // 0..15  (N/128)

  const __bf16* A = (z == 0) ? A0 : (z == 1 ? A1 : A2);
  const __bf16* Bw = Wb + (size_t)z * H_ * H_;
  __bf16* ob = (z == 0) ? o0 : (z == 1 ? o1 : o2);

  const int tid = threadIdx.x;
  const int lane = tid & 63, wv = tid >> 6;   // 4 waves
  const int wm = wv >> 1;           // 0..1
  const int wn = wv & 1;            // 0..1
  const int rr = lane & 15, q = lane >> 4;

  f32x4 acc[4][4];
  #pragma unroll
  for (int m = 0; m < 4; m++)
    #pragma unroll
    for (int n = 0; n < 4; n++) acc[m][n] = (f32x4){0.f, 0.f, 0.f, 0.f};

  const char* Ag = (const char*)A + (size_t)(bm * 128) * (H_ * 2);
  const char* Bg = (const char*)Bw + (size_t)(bn * 128) * (H_ * 2);

  const int srow = wv * 8 + (lane >> 3);            // 0..31 within round
  const int scol = ((lane & 7) ^ (lane >> 3)) << 4; // inverse swizzle
  const int rsw = rr & 7;                            // ds_read swizzle

#define STAGE_TILE(kt_, buf_)                                                   \
  {                                                                             \
    char* base_ = ring[buf_];                                                   \
    _Pragma("unroll")                                                           \
    for (int mh_ = 0; mh_ < 2; mh_++) {                                         \
      const char* Mg_ = mh_ ? Bg : Ag;                                          \
      _Pragma("unroll")                                                         \
      for (int rd_ = 0; rd_ < 4; rd_++) {                                       \
        char* dst_ = base_ + mh_ * 16384 + rd_ * 4096 + wv * 1024;              \
        const char* src_ = Mg_ + (size_t)(rd_ * 32 + srow) * (H_ * 2)           \
                           + (kt_) * 128 + scol;                                \
        async16(src_, dst_);                                                    \
      }                                                                         \
    }                                                                           \
  }

  STAGE_TILE(0, 0);
  asm volatile("s_waitcnt vmcnt(0)" ::: "memory");
  __builtin_amdgcn_s_barrier();

  for (int kt = 0; kt < NKT_; kt++) {
    const int cur = kt & 1, nxt = cur ^ 1;
    const char* Alds = ring[cur];
    const char* Blds = ring[cur] + 16384;

    if (kt + 1 < NKT_) STAGE_TILE(kt + 1, nxt);

    bf16x8 bfr[4][2];
    #pragma unroll
    for (int ni = 0; ni < 4; ni++)
      #pragma unroll
      for (int ks = 0; ks < 2; ks++) {
        int row_t = wn * 64 + ni * 16 + rr;
        bfr[ni][ks] = *(const bf16x8*)(Blds + row_t * 128 +
                                       (((ks * 4 + q) ^ rsw) << 4));
      }

    __builtin_amdgcn_s_setprio(1);
    #pragma unroll
    for (int mi = 0; mi < 4; mi++) {
      bf16x8 af[2];
      #pragma unroll
      for (int ks = 0; ks < 2; ks++) {
        int row_t = wm * 64 + mi * 16 + rr;
        af[ks] = *(const bf16x8*)(Alds + row_t * 128 +
                                  (((ks * 4 + q) ^ rsw) << 4));
      }
      #pragma unroll
      for (int ks = 0; ks < 2; ks++)
        #pragma unroll
        for (int ni = 0; ni < 4; ni++)
          acc[mi][ni] = __builtin_amdgcn_mfma_f32_16x16x32_bf16(
              af[ks], bfr[ni][ks], acc[mi][ni], 0, 0, 0);
    }
    __builtin_amdgcn_s_setprio(0);

    if (kt + 1 < NKT_) {
      asm volatile("s_waitcnt vmcnt(0)" ::: "memory");
      __builtin_amdgcn_s_barrier();
    }
  }
#undef STAGE_TILE

  const int r0 = bm * 128 + wm * 64 + q * 4;
  const int c0 = bn * 128 + wn * 64 + rr;
  #pragma unroll
  for (int mi = 0; mi < 4; mi++) {
    #pragma unroll
    for (int ni = 0; ni < 4; ni++) {
      int col = c0 + ni * 16;
      #pragma unroll
      for (int rg = 0; rg < 4; rg++) {
        int rowg = r0 + mi * 16 + rg;
        size_t idx = (size_t)rowg * H_ + col;
        float vv = acc[mi][ni][rg];
        if (z == 2) {
          ob[idx] = (__bf16)(1.f / (1.f + __expf(-vv)));
        } else {
          ob[idx] = (__bf16)vv;
        }
      }
    }
  }
}

// ----------------------- Wo bf16 NT GEMM, 128^2 tile (kvr structure)
// Same verified schedule/map/setprio as gemm_kvr (65.7 us/GEMM-eq regime);
// epilogue = f32 residual add.  Grid 1024, XCD bm-first chunks.
__global__ __launch_bounds__(256, 2) void gemm_wo128(
    const __bf16* __restrict__ A, const __bf16* __restrict__ Bw,
    float* __restrict__ outf, const float* __restrict__ resid) {
  __shared__ __align__(16) char ring[2][32768];   // [buf][A 16K | B 16K]

  const int g = blockIdx.x;             // 0..1023
  const int x = g & 7;                  // XCD
  const int i = g >> 3;                 // 0..127 within XCD chunk
  const int bm = x * 8 + (i & 7);       // 0..63, bm-first
  const int bn = i >> 3;                // 0..15

  const int tid = threadIdx.x;
  const int lane = tid & 63, wv = tid >> 6;   // 4 waves
  const int wm = wv >> 1;
  const int wn = wv & 1;
  const int rr = lane & 15, q = lane >> 4;

  f32x4 acc[4][4];
  #pragma unroll
  for (int m = 0; m < 4; m++)
    #pragma unroll
    for (int n = 0; n < 4; n++) acc[m][n] = (f32x4){0.f, 0.f, 0.f, 0.f};

  const char* Ag = (const char*)A + (size_t)(bm * 128) * (H_ * 2);
  const char* Bg = (const char*)Bw + (size_t)(bn * 128) * (H_ * 2);

  const int srow = wv * 8 + (lane >> 3);
  const int scol = ((lane & 7) ^ (lane >> 3)) << 4;
  const int rsw = rr & 7;

#define STAGE_TILE(kt_, buf_)                                                   \
  {                                                                             \
    char* base_ = ring[buf_];                                                   \
    _Pragma("unroll")                                                           \
    for (int mh_ = 0; mh_ < 2; mh_++) {                                         \
      const char* Mg_ = mh_ ? Bg : Ag;                                          \
      _Pragma("unroll")                                                         \
      for (int rd_ = 0; rd_ < 4; rd_++) {                                       \
        char* dst_ = base_ + mh_ * 16384 + rd_ * 4096 + wv * 1024;              \
        const char* src_ = Mg_ + (size_t)(rd_ * 32 + srow) * (H_ * 2)           \
                           + (kt_) * 128 + scol;                                \
        async16(src_, dst_);                                                    \
      }                                                                         \
    }                                                                           \
  }

  STAGE_TILE(0, 0);
  asm volatile("s_waitcnt vmcnt(0)" ::: "memory");
  __builtin_amdgcn_s_barrier();

  for (int kt = 0; kt < NKT_; kt++) {
    const int cur = kt & 1, nxt = cur ^ 1;
    const char* Alds = ring[cur];
    const char* Blds = ring[cur] + 16384;

    if (kt + 1 < NKT_) STAGE_TILE(kt + 1, nxt);

    bf16x8 bfr[4][2];
    #pragma unroll
    for (int ni = 0; ni < 4; ni++)
      #pragma unroll
      for (int ks = 0; ks < 2; ks++) {
        int row_t = wn * 64 + ni * 16 + rr;
        bfr[ni][ks] = *(const bf16x8*)(Blds + row_t * 128 +
                                       (((ks * 4 + q) ^ rsw) << 4));
      }

    __builtin_amdgcn_s_setprio(1);
    #pragma unroll
    for (int mi = 0; mi < 4; mi++) {
      bf16x8 af[2];
      #pragma unroll
      for (int ks = 0; ks < 2; ks++) {
        int row_t = wm * 64 + mi * 16 + rr;
        af[ks] = *(const bf16x8*)(Alds + row_t * 128 +
                                  (((ks * 4 + q) ^ rsw) << 4));
      }
      #pragma unroll
      for (int ks = 0; ks < 2; ks++)
        #pragma unroll
        for (int ni = 0; ni < 4; ni++)
          acc[mi][ni] = __builtin_amdgcn_mfma_f32_16x16x32_bf16(
              af[ks], bfr[ni][ks], acc[mi][ni], 0, 0, 0);
    }
    __builtin_amdgcn_s_setprio(0);

    if (kt + 1 < NKT_) {
      asm volatile("s_waitcnt vmcnt(0)" ::: "memory");
      __builtin_amdgcn_s_barrier();
    }
  }
#undef STAGE_TILE

  const int r0 = bm * 128 + wm * 64 + q * 4;
  const int c0 = bn * 128 + wn * 64 + rr;
  #pragma unroll
  for (int mi = 0; mi < 4; mi++) {
    #pragma unroll
    for (int ni = 0; ni < 4; ni++) {
      int col = c0 + ni * 16;
      #pragma unroll
      for (int rg = 0; rg < 4; rg++) {
        int rowg = r0 + mi * 16 + rg;
        size_t idx = (size_t)rowg * H_ + col;
        outf[idx] = resid[idx] + acc[mi][ni][rg];
      }
    }
  }
}

// ------------------------------------------------- WKV chunked scan (3 passes)
__global__ __launch_bounds__(256) void wkv_pass1(
    const __bf16* __restrict__ k, const __bf16* __restrict__ v,
    const float* __restrict__ td,
    float* __restrict__ cs_num, float* __restrict__ cs_den,
    float* __restrict__ cs_norm) {
  const int id = blockIdx.x * 256 + threadIdx.x;  // 0..B*H-1
  const int c = blockIdx.y;                       // chunk
  const int b = id >> 11;
  const int hh = id & (H_ - 1);
  const float decay = -__expf(td[hh]);
  float num = 0.f, den = 0.f, norm = -INFINITY;

  const int UN = 16;
  for (int t0 = c * CL_; t0 < (c + 1) * CL_; t0 += UN) {
    float kk[UN], vv[UN];
    size_t base = ((size_t)b * T_ + t0) * H_ + hh;
    #pragma unroll
    for (int i = 0; i < UN; i++) {
      kk[i] = (float)k[base + (size_t)i * H_];
      vv[i] = (float)v[base + (size_t)i * H_];
    }
    #pragma unroll
    for (int i = 0; i < UN; i++) {
      float dpn = decay + norm;
      float nn = fmaxf(dpn, kk[i]);
      float ed = __expf(dpn - nn), ek = __expf(kk[i] - nn);
      num = ed * num + ek * vv[i];
      den = ed * den + ek;
      norm = nn;
    }
  }
  cs_num[c * BH_ + id] = num;
  cs_den[c * BH_ + id] = den;
  cs_norm[c * BH_ + id] = norm;
}

__global__ __launch_bounds__(256) void wkv_scan(
    const float* __restrict__ cs_num, const float* __restrict__ cs_den,
    const float* __restrict__ cs_norm, const float* __restrict__ td,
    float* __restrict__ px_num, float* __restrict__ px_den,
    float* __restrict__ px_norm) {
  const int id = blockIdx.x * 256 + threadIdx.x;  // 0..B*H-1
  const int hh = id & (H_ - 1);
  const float Lw = -__expf(td[hh]) * (float)CL_;  // CL_ * decay
  float num = 0.f, den = 0.f, norm = -INFINITY;
  for (int c = 0; c < CH_; c++) {
    px_num[c * BH_ + id] = num;
    px_den[c * BH_ + id] = den;
    px_norm[c * BH_ + id] = norm;
    float n_c = cs_num[c * BH_ + id];
    float d_c = cs_den[c * BH_ + id];
    float m_c = cs_norm[c * BH_ + id];
    float sn = norm + Lw;                 // shifted incoming norm
    float on = fmaxf(sn, m_c);            // m_c is always finite
    float ea = __expf(sn - on), eb = __expf(m_c - on);
    num = ea * num + eb * n_c;
    den = ea * den + eb * d_c;
    norm = on;
  }
}

__global__ __launch_bounds__(256) void wkv_pass2(
    const __bf16* __restrict__ k, const __bf16* __restrict__ v,
    const __bf16* __restrict__ r, const float* __restrict__ td,
    const float* __restrict__ cw,
    const float* __restrict__ px_num, const float* __restrict__ px_den,
    const float* __restrict__ px_norm,
    __bf16* __restrict__ a, float* __restrict__ ndn) {
  const int id = blockIdx.x * 256 + threadIdx.x;  // 0..B*H-1
  const int c = blockIdx.y;
  const int b = id >> 11;
  const int hh = id & (H_ - 1);
  const float decay = -__expf(td[hh]);
  const float cwv = cw[hh];
  float num = px_num[c * BH_ + id];
  float den = px_den[c * BH_ + id];
  float norm = px_norm[c * BH_ + id];

  const int UN = 16;
  for (int t0 = c * CL_; t0 < (c + 1) * CL_; t0 += UN) {
    float kk[UN], vv[UN], rrv[UN];
    size_t base = ((size_t)b * T_ + t0) * H_ + hh;
    #pragma unroll
    for (int i = 0; i < UN; i++) {
      kk[i] = (float)k[base + (size_t)i * H_];
      vv[i] = (float)v[base + (size_t)i * H_];
      rrv[i] = (float)r[base + (size_t)i * H_];
    }
    #pragma unroll
    for (int i = 0; i < UN; i++) {
      float kt = kk[i], vt = vv[i];
      float ct = cwv + kt;
      float cn = fmaxf(ct, norm);
      float ep = __expf(norm - cn), ec = __expf(ct - cn);
      float o = (ep * num + ec * vt) / (ep * den + ec);
      a[base + (size_t)i * H_] = (__bf16)(rrv[i] * o);
      float dpn = decay + norm;
      float nn = fmaxf(dpn, kt);
      float ed = __expf(dpn - nn), ek = __expf(kt - nn);
      num = ed * num + ek * vt;
      den = ed * den + ek;
      norm = nn;
    }
  }
  if (c == CH_ - 1) {
    ndn[id] = num;
    ndn[BH_ + id] = den;
    ndn[2 * BH_ + id] = norm;
  }
}

// ----------------------------------------------------------------------- host
extern "C" void kernel_launch(void* const* d_in, const int* in_sizes, int n_in,
                              void* d_out, int out_size, void* d_ws, size_t ws_size,
                              hipStream_t stream) {
  const float* h   = (const float*)d_in[0];
  const float* lnw = (const float*)d_in[1];
  const float* lnb = (const float*)d_in[2];
  const float* Wk  = (const float*)d_in[3];
  const float* Wv  = (const float*)d_in[4];
  const float* Wr  = (const float*)d_in[5];
  const float* Wo  = (const float*)d_in[6];
  const float* mk  = (const float*)d_in[7];
  const float* mv  = (const float*)d_in[8];
  const float* mr  = (const float*)d_in[9];
  const float* td  = (const float*)d_in[10];
  const float* cw  = (const float*)d_in[11];

  char* ws = (char*)d_ws;
  const size_t MB = 1048576;
  // Workspace layout (224 MB of 256):
  //   [0,32)    xk   (bf16, later reused as 'a' = r*wkv)
  //   [32,64)   xv   (bf16)
  //   [64,96)   xr   (bf16; dead after fused GEMM -> scan state (6 MB) here)
  //   [96,128)  kbuf (bf16)
  //   [128,160) vbuf (bf16)
  //   [160,192) W16: Wk/Wv/Wr/Wo bf16, 8 MB each (contiguous)
  //   [192,224) rbuf (bf16)
  __bf16* xk   = (__bf16*)(ws);
  __bf16* xv   = (__bf16*)(ws + 32 * MB);
  __bf16* xr   = (__bf16*)(ws + 64 * MB);
  __bf16* kbuf = (__bf16*)(ws + 96 * MB);
  __bf16* vbuf = (__bf16*)(ws + 128 * MB);
  __bf16* W16  = (__bf16*)(ws + 160 * MB);
  __bf16* rbuf = (__bf16*)(ws + 192 * MB);
  __bf16* Wo16 = W16 + 3 * (size_t)H_ * H_;
  float* cs_num  = (float*)(ws + 64 * MB);     // 6 x CH_*BH_ f32 = 6 MB
  float* cs_den  = cs_num + (size_t)CH_ * BH_;
  float* cs_norm = cs_den + (size_t)CH_ * BH_;
  float* px_num  = cs_norm + (size_t)CH_ * BH_;
  float* px_den  = px_num + (size_t)CH_ * BH_;
  float* px_norm = px_den + (size_t)CH_ * BH_;

  float* out  = (float*)d_out;
  float* xlast = out + (size_t)BT_ * H_;
  float* ndn   = xlast + (size_t)B_ * H_;

  dim3 cg((H_ * H_) / (256 * 8), 4);
  cvt_bf16_kernel<<<cg, 256, 0, stream>>>(Wk, Wv, Wr, Wo, W16);

  ln_mix_kernel<<<BT_, 256, 0, stream>>>(h, lnw, lnb, mk, mv, mr, xk, xv, xr, xlast);

  // fused k/v/r GEMM: 3 x (64 x 16) blocks, per-z XCD swizzle (R10 map) + T5
  gemm_kvr<<<3072, 256, 0, stream>>>(xk, xv, xr, W16, kbuf, vbuf, rbuf);

  dim3 wg(BH_ / 256, CH_);
  wkv_pass1<<<wg, 256, 0, stream>>>(kbuf, vbuf, td, cs_num, cs_den, cs_norm);
  wkv_scan<<<BH_ / 256, 256, 0, stream>>>(cs_num, cs_den, cs_norm, td,
                                          px_num, px_den, px_norm);
  wkv_pass2<<<wg, 256, 0, stream>>>(kbuf, vbuf, rbuf, td, cw,
                                    px_num, px_den, px_norm,
                                    xk /* a reuses xk */, ndn);

  // Wo GEMM + residual, 128^2 kvr-structure (2 blocks/CU + setprio)
  gemm_wo128<<<1024, 256, 0, stream>>>(xk, Wo16, out, h);
}

// Round 15
// 376.849 us; speedup vs baseline: 1.0336x; 1.0336x over previous
//
#include <hip/hip_runtime.h>
#include <hip/hip_bf16.h>
#include <stdint.h>

// RWKV4 time-mix for B=4, T=2048, H=2048 on gfx950.
#define B_ 4
#define T_ 2048
#define H_ 2048
#define BT_ (B_ * T_)
#define BH_ (B_ * H_)
#define CH_ 32              // number of time chunks for the WKV scan
#define CL_ (T_ / CH_)      // chunk length = 64
#define NKT_ (H_ / 64)      // 32 K-tiles of BK=64 for the GEMM

typedef __bf16 bf16x8 __attribute__((ext_vector_type(8)));
typedef float f32x4 __attribute__((ext_vector_type(4)));

// async global->LDS, 16B per lane. LDS dest is wave-uniform base + lane*16.
__device__ inline void async16(const void* g, void* l) {
  __builtin_amdgcn_global_load_lds(
      (__attribute__((address_space(1))) uint32_t*)(void*)(uintptr_t)g,
      (__attribute__((address_space(3))) uint32_t*)l,
      16, 0, 0);
}

// ------------------------------------------- f32 -> bf16 (all 4 weights, 1 launch)
__global__ __launch_bounds__(256) void cvt_bf16_kernel(
    const float* __restrict__ w0, const float* __restrict__ w1,
    const float* __restrict__ w2, const float* __restrict__ w3,
    __bf16* __restrict__ dst /* 4 contiguous H*H blocks */) {
  const float* srcs[4] = {w0, w1, w2, w3};
  const float* src = srcs[blockIdx.y];
  __bf16* d = dst + (size_t)blockIdx.y * H_ * H_;
  int i = (blockIdx.x * 256 + threadIdx.x) * 8;
  const float4* s4 = (const float4*)(src + i);
  float4 a = s4[0], b = s4[1];
  bf16x8 o;
  o[0] = (__bf16)a.x; o[1] = (__bf16)a.y; o[2] = (__bf16)a.z; o[3] = (__bf16)a.w;
  o[4] = (__bf16)b.x; o[5] = (__bf16)b.y; o[6] = (__bf16)b.z; o[7] = (__bf16)b.w;
  *(bf16x8*)(d + i) = o;
}

// ------------------------------------------------- LayerNorm + token-shift mix
__global__ __launch_bounds__(256) void ln_mix_kernel(
    const float* __restrict__ h, const float* __restrict__ lnw,
    const float* __restrict__ lnb, const float* __restrict__ mk,
    const float* __restrict__ mv, const float* __restrict__ mr,
    __bf16* __restrict__ xk, __bf16* __restrict__ xv, __bf16* __restrict__ xr,
    float* __restrict__ xlast) {
  const int row = blockIdx.x;          // b*T + t
  const int t = row & (T_ - 1);
  const int tid = threadIdx.x;
  const bool hasprev = (t != 0);

  const float4* cr = (const float4*)(h + (size_t)row * H_);
  float4 c0 = cr[tid * 2 + 0], c1 = cr[tid * 2 + 1];
  float4 p0 = {0.f, 0.f, 0.f, 0.f}, p1 = {0.f, 0.f, 0.f, 0.f};
  if (hasprev) {
    const float4* pr = (const float4*)(h + (size_t)(row - 1) * H_);
    p0 = pr[tid * 2 + 0]; p1 = pr[tid * 2 + 1];
  }
  float4 red;
  red.x = c0.x + c0.y + c0.z + c0.w + c1.x + c1.y + c1.z + c1.w;
  red.y = c0.x * c0.x + c0.y * c0.y + c0.z * c0.z + c0.w * c0.w +
          c1.x * c1.x + c1.y * c1.y + c1.z * c1.z + c1.w * c1.w;
  red.z = p0.x + p0.y + p0.z + p0.w + p1.x + p1.y + p1.z + p1.w;
  red.w = p0.x * p0.x + p0.y * p0.y + p0.z * p0.z + p0.w * p0.w +
          p1.x * p1.x + p1.y * p1.y + p1.z * p1.z + p1.w * p1.w;
  #pragma unroll
  for (int off = 32; off; off >>= 1) {
    red.x += __shfl_down(red.x, off);
    red.y += __shfl_down(red.y, off);
    red.z += __shfl_down(red.z, off);
    red.w += __shfl_down(red.w, off);
  }
  __shared__ float4 rbuf_[4];
  const int lane = tid & 63, wid = tid >> 6;
  if (lane == 0) rbuf_[wid] = red;
  __syncthreads();
  float4 tot;
  tot.x = rbuf_[0].x + rbuf_[1].x + rbuf_[2].x + rbuf_[3].x;
  tot.y = rbuf_[0].y + rbuf_[1].y + rbuf_[2].y + rbuf_[3].y;
  tot.z = rbuf_[0].z + rbuf_[1].z + rbuf_[2].z + rbuf_[3].z;
  tot.w = rbuf_[0].w + rbuf_[1].w + rbuf_[2].w + rbuf_[3].w;

  const float inv = 1.0f / (float)H_;
  float mu = tot.x * inv;
  float rstd = rsqrtf(fmaxf(tot.y * inv - mu * mu, 0.f) + 1e-5f);
  float mup = tot.z * inv;
  float rstdp = rsqrtf(fmaxf(tot.w * inv - mup * mup, 0.f) + 1e-5f);

  float xc[8] = {c0.x, c0.y, c0.z, c0.w, c1.x, c1.y, c1.z, c1.w};
  float xp[8] = {p0.x, p0.y, p0.z, p0.w, p1.x, p1.y, p1.z, p1.w};
  const float4* W4 = (const float4*)lnw;
  const float4* Bv4 = (const float4*)lnb;
  const float4* MK4 = (const float4*)mk;
  const float4* MV4 = (const float4*)mv;
  const float4* MR4 = (const float4*)mr;
  float4 w0 = W4[tid * 2], w1 = W4[tid * 2 + 1];
  float4 b0 = Bv4[tid * 2], b1 = Bv4[tid * 2 + 1];
  float4 k0 = MK4[tid * 2], k1 = MK4[tid * 2 + 1];
  float4 v0 = MV4[tid * 2], v1 = MV4[tid * 2 + 1];
  float4 r0 = MR4[tid * 2], r1 = MR4[tid * 2 + 1];
  float wa[8] = {w0.x, w0.y, w0.z, w0.w, w1.x, w1.y, w1.z, w1.w};
  float ba[8] = {b0.x, b0.y, b0.z, b0.w, b1.x, b1.y, b1.z, b1.w};
  float ka[8] = {k0.x, k0.y, k0.z, k0.w, k1.x, k1.y, k1.z, k1.w};
  float va[8] = {v0.x, v0.y, v0.z, v0.w, v1.x, v1.y, v1.z, v1.w};
  float ra[8] = {r0.x, r0.y, r0.z, r0.w, r1.x, r1.y, r1.z, r1.w};

  bf16x8 ok_, ov_, or_;
  float xls[8];
  #pragma unroll
  for (int e = 0; e < 8; e++) {
    float x = (xc[e] - mu) * rstd * wa[e] + ba[e];
    float sx = hasprev ? (xp[e] - mup) * rstdp * wa[e] + ba[e] : 0.f;
    ok_[e] = (__bf16)(sx + ka[e] * (x - sx));
    ov_[e] = (__bf16)(sx + va[e] * (x - sx));
    or_[e] = (__bf16)(sx + ra[e] * (x - sx));
    xls[e] = x;
  }
  size_t obase = (size_t)row * H_ + tid * 8;
  *(bf16x8*)(xk + obase) = ok_;
  *(bf16x8*)(xv + obase) = ov_;
  *(bf16x8*)(xr + obase) = or_;
  if (t == T_ - 1) {
    float* dst = xlast + (size_t)(row >> 11) * H_ + tid * 8;
    #pragma unroll
    for (int e = 0; e < 8; e++) dst[e] = xls[e];
  }
}

// ----------------------- fused k/v/r bf16 NT GEMM, 128^2 tile, BK=64
// R10 map (per-z XCD swizzle, bm-first chunk) + R12 setprio (T5).
// Verified: ~197 us for 3 GEMM-equivalents, MfmaUtil 48%.
__global__ __launch_bounds__(256, 2) void gemm_kvr(
    const __bf16* __restrict__ A0, const __bf16* __restrict__ A1,
    const __bf16* __restrict__ A2, const __bf16* __restrict__ Wb,
    __bf16* __restrict__ o0, __bf16* __restrict__ o1, __bf16* __restrict__ o2) {
  __shared__ __align__(16) char ring[2][32768];   // [buf][A 16K | B 16K]

  // z-slab, then per-z bijective XCD swizzle with bm-first chunk order.
  const int wgid = blockIdx.x;          // 0..3071
  const int z = wgid >> 10;             // 0..2
  const int g = wgid & 1023;
  const int x = g & 7;                  // XCD
  const int i = g >> 3;                 // 0..127 within XCD chunk
  const int bm = x * 8 + (i & 7);       // 0..63  (M/128), bm-first
  const int bn = i >> 3;                // 0..15  (N/128)

  const __bf16* A = (z == 0) ? A0 : (z == 1 ? A1 : A2);
  const __bf16* Bw = Wb + (size_t)z * H_ * H_;
  __bf16* ob = (z == 0) ? o0 : (z == 1 ? o1 : o2);

  const int tid = threadIdx.x;
  const int lane = tid & 63, wv = tid >> 6;   // 4 waves
  const int wm = wv >> 1;           // 0..1
  const int wn = wv & 1;            // 0..1
  const int rr = lane & 15, q = lane >> 4;

  f32x4 acc[4][4];
  #pragma unroll
  for (int m = 0; m < 4; m++)
    #pragma unroll
    for (int n = 0; n < 4; n++) acc[m][n] = (f32x4){0.f, 0.f, 0.f, 0.f};

  const char* Ag = (const char*)A + (size_t)(bm * 128) * (H_ * 2);
  const char* Bg = (const char*)Bw + (size_t)(bn * 128) * (H_ * 2);

  const int srow = wv * 8 + (lane >> 3);            // 0..31 within round
  const int scol = ((lane & 7) ^ (lane >> 3)) << 4; // inverse swizzle
  const int rsw = rr & 7;                            // ds_read swizzle

#define STAGE_TILE(kt_, buf_)                                                   \
  {                                                                             \
    char* base_ = ring[buf_];                                                   \
    _Pragma("unroll")                                                           \
    for (int mh_ = 0; mh_ < 2; mh_++) {                                         \
      const char* Mg_ = mh_ ? Bg : Ag;                                          \
      _Pragma("unroll")                                                         \
      for (int rd_ = 0; rd_ < 4; rd_++) {                                       \
        char* dst_ = base_ + mh_ * 16384 + rd_ * 4096 + wv * 1024;              \
        const char* src_ = Mg_ + (size_t)(rd_ * 32 + srow) * (H_ * 2)           \
                           + (kt_) * 128 + scol;                                \
        async16(src_, dst_);                                                    \
      }                                                                         \
    }                                                                           \
  }

  STAGE_TILE(0, 0);
  asm volatile("s_waitcnt vmcnt(0)" ::: "memory");
  __builtin_amdgcn_s_barrier();

  for (int kt = 0; kt < NKT_; kt++) {
    const int cur = kt & 1, nxt = cur ^ 1;
    const char* Alds = ring[cur];
    const char* Blds = ring[cur] + 16384;

    if (kt + 1 < NKT_) STAGE_TILE(kt + 1, nxt);

    bf16x8 bfr[4][2];
    #pragma unroll
    for (int ni = 0; ni < 4; ni++)
      #pragma unroll
      for (int ks = 0; ks < 2; ks++) {
        int row_t = wn * 64 + ni * 16 + rr;
        bfr[ni][ks] = *(const bf16x8*)(Blds + row_t * 128 +
                                       (((ks * 4 + q) ^ rsw) << 4));
      }

    __builtin_amdgcn_s_setprio(1);
    #pragma unroll
    for (int mi = 0; mi < 4; mi++) {
      bf16x8 af[2];
      #pragma unroll
      for (int ks = 0; ks < 2; ks++) {
        int row_t = wm * 64 + mi * 16 + rr;
        af[ks] = *(const bf16x8*)(Alds + row_t * 128 +
                                  (((ks * 4 + q) ^ rsw) << 4));
      }
      #pragma unroll
      for (int ks = 0; ks < 2; ks++)
        #pragma unroll
        for (int ni = 0; ni < 4; ni++)
          acc[mi][ni] = __builtin_amdgcn_mfma_f32_16x16x32_bf16(
              af[ks], bfr[ni][ks], acc[mi][ni], 0, 0, 0);
    }
    __builtin_amdgcn_s_setprio(0);

    if (kt + 1 < NKT_) {
      asm volatile("s_waitcnt vmcnt(0)" ::: "memory");
      __builtin_amdgcn_s_barrier();
    }
  }
#undef STAGE_TILE

  const int r0 = bm * 128 + wm * 64 + q * 4;
  const int c0 = bn * 128 + wn * 64 + rr;
  #pragma unroll
  for (int mi = 0; mi < 4; mi++) {
    #pragma unroll
    for (int ni = 0; ni < 4; ni++) {
      int col = c0 + ni * 16;
      #pragma unroll
      for (int rg = 0; rg < 4; rg++) {
        int rowg = r0 + mi * 16 + rg;
        size_t idx = (size_t)rowg * H_ + col;
        float vv = acc[mi][ni][rg];
        if (z == 2) {
          ob[idx] = (__bf16)(1.f / (1.f + __expf(-vv)));
        } else {
          ob[idx] = (__bf16)vv;
        }
      }
    }
  }
}

// ----------------------- Wo bf16 NT GEMM, 256^2 tile (R8 verified, 78 us)
__global__ __launch_bounds__(512, 1) void gemm_wo(
    const __bf16* __restrict__ A, const __bf16* __restrict__ Bw,
    float* __restrict__ outf, const float* __restrict__ resid) {
  __shared__ __align__(16) char ring[2][65536];   // [buf][A 32K | B 32K]

  const int wgid = blockIdx.x;
  const int lin = (wgid & 7) * 32 + (wgid >> 3);
  const int bm = lin >> 3;          // 0..31
  const int bn = lin & 7;           // 0..7

  const int tid = threadIdx.x;
  const int lane = tid & 63, wv = tid >> 6;
  const int wm = wv >> 2;           // 0..1
  const int wn = wv & 3;            // 0..3
  const int rr = lane & 15, q = lane >> 4;

  f32x4 acc[8][4];
  #pragma unroll
  for (int m = 0; m < 8; m++)
    #pragma unroll
    for (int n = 0; n < 4; n++) acc[m][n] = (f32x4){0.f, 0.f, 0.f, 0.f};

  const char* Ag = (const char*)A + (size_t)(bm * 256) * (H_ * 2);
  const char* Bg = (const char*)Bw + (size_t)(bn * 256) * (H_ * 2);

  const int srow = wv * 8 + (lane >> 3);
  const int scol = ((lane & 7) ^ (lane >> 3)) << 4;
  const int rsw = rr & 7;

#define STAGE_TILE(kt_, buf_)                                                   \
  {                                                                             \
    char* base_ = ring[buf_];                                                   \
    _Pragma("unroll")                                                           \
    for (int mh_ = 0; mh_ < 2; mh_++) {                                         \
      const char* Mg_ = mh_ ? Bg : Ag;                                          \
      _Pragma("unroll")                                                         \
      for (int hh_ = 0; hh_ < 2; hh_++) {                                       \
        _Pragma("unroll")                                                       \
        for (int rd_ = 0; rd_ < 2; rd_++) {                                     \
          char* dst_ = base_ + mh_ * 32768 + hh_ * 16384 + rd_ * 8192 + wv * 1024; \
          const char* src_ = Mg_ + (size_t)(hh_ * 128 + rd_ * 64 + srow) * (H_ * 2) \
                             + (kt_) * 128 + scol;                              \
          async16(src_, dst_);                                                  \
        }                                                                       \
      }                                                                         \
    }                                                                           \
  }

  STAGE_TILE(0, 0);
  asm volatile("s_waitcnt vmcnt(0)" ::: "memory");
  __builtin_amdgcn_s_barrier();

  for (int kt = 0; kt < NKT_; kt++) {
    const int cur = kt & 1, nxt = cur ^ 1;
    const char* Alds = ring[cur];
    const char* Blds = ring[cur] + 32768;

    if (kt + 1 < NKT_) STAGE_TILE(kt + 1, nxt);

    bf16x8 bfr[4][2];
    #pragma unroll
    for (int ni = 0; ni < 4; ni++)
      #pragma unroll
      for (int ks = 0; ks < 2; ks++) {
        int row_t = wn * 64 + ni * 16 + rr;
        bfr[ni][ks] = *(const bf16x8*)(Blds + row_t * 128 +
                                       (((ks * 4 + q) ^ rsw) << 4));
      }

    #pragma unroll
    for (int p = 0; p < 4; p++) {
      bf16x8 af[2][2];
      #pragma unroll
      for (int mi = 0; mi < 2; mi++)
        #pragma unroll
        for (int ks = 0; ks < 2; ks++) {
          int row_t = wm * 128 + p * 32 + mi * 16 + rr;
          af[mi][ks] = *(const bf16x8*)(Alds + row_t * 128 +
                                        (((ks * 4 + q) ^ rsw) << 4));
        }
      #pragma unroll
      for (int ks = 0; ks < 2; ks++)
        #pragma unroll
        for (int mi = 0; mi < 2; mi++)
          #pragma unroll
          for (int ni = 0; ni < 4; ni++)
            acc[p * 2 + mi][ni] = __builtin_amdgcn_mfma_f32_16x16x32_bf16(
                af[mi][ks], bfr[ni][ks], acc[p * 2 + mi][ni], 0, 0, 0);
    }

    if (kt + 1 < NKT_) {
      asm volatile("s_waitcnt vmcnt(0)" ::: "memory");
      __builtin_amdgcn_s_barrier();
    }
  }
#undef STAGE_TILE

  const int r0 = bm * 256 + wm * 128 + q * 4;
  const int c0 = bn * 256 + wn * 64 + rr;
  #pragma unroll
  for (int m = 0; m < 8; m++) {
    #pragma unroll
    for (int n = 0; n < 4; n++) {
      int col = c0 + n * 16;
      #pragma unroll
      for (int rg = 0; rg < 4; rg++) {
        int rowg = r0 + m * 16 + rg;
        size_t idx = (size_t)rowg * H_ + col;
        outf[idx] = resid[idx] + acc[m][n][rg];
      }
    }
  }
}

// ------------------------------------------------- WKV chunked scan (3 passes)
__global__ __launch_bounds__(256) void wkv_pass1(
    const __bf16* __restrict__ k, const __bf16* __restrict__ v,
    const float* __restrict__ td,
    float* __restrict__ cs_num, float* __restrict__ cs_den,
    float* __restrict__ cs_norm) {
  const int id = blockIdx.x * 256 + threadIdx.x;  // 0..B*H-1
  const int c = blockIdx.y;                       // chunk
  const int b = id >> 11;
  const int hh = id & (H_ - 1);
  const float decay = -__expf(td[hh]);
  float num = 0.f, den = 0.f, norm = -INFINITY;

  const int UN = 16;
  for (int t0 = c * CL_; t0 < (c + 1) * CL_; t0 += UN) {
    float kk[UN], vv[UN];
    size_t base = ((size_t)b * T_ + t0) * H_ + hh;
    #pragma unroll
    for (int i = 0; i < UN; i++) {
      kk[i] = (float)k[base + (size_t)i * H_];
      vv[i] = (float)v[base + (size_t)i * H_];
    }
    #pragma unroll
    for (int i = 0; i < UN; i++) {
      float dpn = decay + norm;
      float nn = fmaxf(dpn, kk[i]);
      float ed = __expf(dpn - nn), ek = __expf(kk[i] - nn);
      num = ed * num + ek * vv[i];
      den = ed * den + ek;
      norm = nn;
    }
  }
  cs_num[c * BH_ + id] = num;
  cs_den[c * BH_ + id] = den;
  cs_norm[c * BH_ + id] = norm;
}

__global__ __launch_bounds__(256) void wkv_scan(
    const float* __restrict__ cs_num, const float* __restrict__ cs_den,
    const float* __restrict__ cs_norm, const float* __restrict__ td,
    float* __restrict__ px_num, float* __restrict__ px_den,
    float* __restrict__ px_norm) {
  const int id = blockIdx.x * 256 + threadIdx.x;  // 0..B*H-1
  const int hh = id & (H_ - 1);
  const float Lw = -__expf(td[hh]) * (float)CL_;  // CL_ * decay
  float num = 0.f, den = 0.f, norm = -INFINITY;
  for (int c = 0; c < CH_; c++) {
    px_num[c * BH_ + id] = num;
    px_den[c * BH_ + id] = den;
    px_norm[c * BH_ + id] = norm;
    float n_c = cs_num[c * BH_ + id];
    float d_c = cs_den[c * BH_ + id];
    float m_c = cs_norm[c * BH_ + id];
    float sn = norm + Lw;                 // shifted incoming norm
    float on = fmaxf(sn, m_c);            // m_c is always finite
    float ea = __expf(sn - on), eb = __expf(m_c - on);
    num = ea * num + eb * n_c;
    den = ea * den + eb * d_c;
    norm = on;
  }
}

__global__ __launch_bounds__(256) void wkv_pass2(
    const __bf16* __restrict__ k, const __bf16* __restrict__ v,
    const __bf16* __restrict__ r, const float* __restrict__ td,
    const float* __restrict__ cw,
    const float* __restrict__ px_num, const float* __restrict__ px_den,
    const float* __restrict__ px_norm,
    __bf16* __restrict__ a, float* __restrict__ ndn) {
  const int id = blockIdx.x * 256 + threadIdx.x;  // 0..B*H-1
  const int c = blockIdx.y;
  const int b = id >> 11;
  const int hh = id & (H_ - 1);
  const float decay = -__expf(td[hh]);
  const float cwv = cw[hh];
  float num = px_num[c * BH_ + id];
  float den = px_den[c * BH_ + id];
  float norm = px_norm[c * BH_ + id];

  const int UN = 16;
  for (int t0 = c * CL_; t0 < (c + 1) * CL_; t0 += UN) {
    float kk[UN], vv[UN], rrv[UN];
    size_t base = ((size_t)b * T_ + t0) * H_ + hh;
    #pragma unroll
    for (int i = 0; i < UN; i++) {
      kk[i] = (float)k[base + (size_t)i * H_];
      vv[i] = (float)v[base + (size_t)i * H_];
      rrv[i] = (float)r[base + (size_t)i * H_];
    }
    #pragma unroll
    for (int i = 0; i < UN; i++) {
      float kt = kk[i], vt = vv[i];
      float ct = cwv + kt;
      float cn = fmaxf(ct, norm);
      float ep = __expf(norm - cn), ec = __expf(ct - cn);
      float o = (ep * num + ec * vt) / (ep * den + ec);
      a[base + (size_t)i * H_] = (__bf16)(rrv[i] * o);
      float dpn = decay + norm;
      float nn = fmaxf(dpn, kt);
      float ed = __expf(dpn - nn), ek = __expf(kt - nn);
      num = ed * num + ek * vt;
      den = ed * den + ek;
      norm = nn;
    }
  }
  if (c == CH_ - 1) {
    ndn[id] = num;
    ndn[BH_ + id] = den;
    ndn[2 * BH_ + id] = norm;
  }
}

// ----------------------------------------------------------------------- host
extern "C" void kernel_launch(void* const* d_in, const int* in_sizes, int n_in,
                              void* d_out, int out_size, void* d_ws, size_t ws_size,
                              hipStream_t stream) {
  const float* h   = (const float*)d_in[0];
  const float* lnw = (const float*)d_in[1];
  const float* lnb = (const float*)d_in[2];
  const float* Wk  = (const float*)d_in[3];
  const float* Wv  = (const float*)d_in[4];
  const float* Wr  = (const float*)d_in[5];
  const float* Wo  = (const float*)d_in[6];
  const float* mk  = (const float*)d_in[7];
  const float* mv  = (const float*)d_in[8];
  const float* mr  = (const float*)d_in[9];
  const float* td  = (const float*)d_in[10];
  const float* cw  = (const float*)d_in[11];

  char* ws = (char*)d_ws;
  const size_t MB = 1048576;
  // Workspace layout (224 MB of 256):
  //   [0,32)    xk   (bf16, later reused as 'a' = r*wkv)
  //   [32,64)   xv   (bf16)
  //   [64,96)   xr   (bf16; dead after fused GEMM -> scan state (6 MB) here)
  //   [96,128)  kbuf (bf16)
  //   [128,160) vbuf (bf16)
  //   [160,192) W16: Wk/Wv/Wr/Wo bf16, 8 MB each (contiguous)
  //   [192,224) rbuf (bf16)
  __bf16* xk   = (__bf16*)(ws);
  __bf16* xv   = (__bf16*)(ws + 32 * MB);
  __bf16* xr   = (__bf16*)(ws + 64 * MB);
  __bf16* kbuf = (__bf16*)(ws + 96 * MB);
  __bf16* vbuf = (__bf16*)(ws + 128 * MB);
  __bf16* W16  = (__bf16*)(ws + 160 * MB);
  __bf16* rbuf = (__bf16*)(ws + 192 * MB);
  __bf16* Wo16 = W16 + 3 * (size_t)H_ * H_;
  float* cs_num  = (float*)(ws + 64 * MB);     // 6 x CH_*BH_ f32 = 6 MB
  float* cs_den  = cs_num + (size_t)CH_ * BH_;
  float* cs_norm = cs_den + (size_t)CH_ * BH_;
  float* px_num  = cs_norm + (size_t)CH_ * BH_;
  float* px_den  = px_num + (size_t)CH_ * BH_;
  float* px_norm = px_den + (size_t)CH_ * BH_;

  float* out  = (float*)d_out;
  float* xlast = out + (size_t)BT_ * H_;
  float* ndn   = xlast + (size_t)B_ * H_;

  dim3 cg((H_ * H_) / (256 * 8), 4);
  cvt_bf16_kernel<<<cg, 256, 0, stream>>>(Wk, Wv, Wr, Wo, W16);

  ln_mix_kernel<<<BT_, 256, 0, stream>>>(h, lnw, lnb, mk, mv, mr, xk, xv, xr, xlast);

  // fused k/v/r GEMM: 3 x (64 x 16) blocks, per-z XCD swizzle (R10 map) + T5
  gemm_kvr<<<3072, 256, 0, stream>>>(xk, xv, xr, W16, kbuf, vbuf, rbuf);

  dim3 wg(BH_ / 256, CH_);
  wkv_pass1<<<wg, 256, 0, stream>>>(kbuf, vbuf, td, cs_num, cs_den, cs_norm);
  wkv_scan<<<BH_ / 256, 256, 0, stream>>>(cs_num, cs_den, cs_norm, td,
                                          px_num, px_den, px_norm);
  wkv_pass2<<<wg, 256, 0, stream>>>(kbuf, vbuf, rbuf, td, cw,
                                    px_num, px_den, px_norm,
                                    xk /* a reuses xk */, ndn);

  // Wo GEMM + residual at 256^2 (R8-verified fast variant)
  gemm_wo<<<256, 512, 0, stream>>>(xk, Wo16, out, h);
}

// Round 16
// 374.936 us; speedup vs baseline: 1.0389x; 1.0051x over previous
//
#include <hip/hip_runtime.h>
#include <hip/hip_bf16.h>
#include <stdint.h>

// RWKV4 time-mix for B=4, T=2048, H=2048 on gfx950.
#define B_ 4
#define T_ 2048
#define H_ 2048
#define BT_ (B_ * T_)
#define BH_ (B_ * H_)
#define CH_ 32              // number of time chunks for the WKV scan
#define CL_ (T_ / CH_)      // chunk length = 64
#define NKT_ (H_ / 64)      // 32 K-tiles of BK=64 for the GEMM

typedef __bf16 bf16x8 __attribute__((ext_vector_type(8)));
typedef float f32x4 __attribute__((ext_vector_type(4)));

// async global->LDS, 16B per lane. LDS dest is wave-uniform base + lane*16.
__device__ inline void async16(const void* g, void* l) {
  __builtin_amdgcn_global_load_lds(
      (__attribute__((address_space(1))) uint32_t*)(void*)(uintptr_t)g,
      (__attribute__((address_space(3))) uint32_t*)l,
      16, 0, 0);
}

// ------------------------------------------- f32 -> bf16 (all 4 weights, 1 launch)
__global__ __launch_bounds__(256) void cvt_bf16_kernel(
    const float* __restrict__ w0, const float* __restrict__ w1,
    const float* __restrict__ w2, const float* __restrict__ w3,
    __bf16* __restrict__ dst /* 4 contiguous H*H blocks */) {
  const float* srcs[4] = {w0, w1, w2, w3};
  const float* src = srcs[blockIdx.y];
  __bf16* d = dst + (size_t)blockIdx.y * H_ * H_;
  int i = (blockIdx.x * 256 + threadIdx.x) * 8;
  const float4* s4 = (const float4*)(src + i);
  float4 a = s4[0], b = s4[1];
  bf16x8 o;
  o[0] = (__bf16)a.x; o[1] = (__bf16)a.y; o[2] = (__bf16)a.z; o[3] = (__bf16)a.w;
  o[4] = (__bf16)b.x; o[5] = (__bf16)b.y; o[6] = (__bf16)b.z; o[7] = (__bf16)b.w;
  *(bf16x8*)(d + i) = o;
}

// ------------------------------------------------- LayerNorm + token-shift mix
__global__ __launch_bounds__(256) void ln_mix_kernel(
    const float* __restrict__ h, const float* __restrict__ lnw,
    const float* __restrict__ lnb, const float* __restrict__ mk,
    const float* __restrict__ mv, const float* __restrict__ mr,
    __bf16* __restrict__ xk, __bf16* __restrict__ xv, __bf16* __restrict__ xr,
    float* __restrict__ xlast) {
  const int row = blockIdx.x;          // b*T + t
  const int t = row & (T_ - 1);
  const int tid = threadIdx.x;
  const bool hasprev = (t != 0);

  const float4* cr = (const float4*)(h + (size_t)row * H_);
  float4 c0 = cr[tid * 2 + 0], c1 = cr[tid * 2 + 1];
  float4 p0 = {0.f, 0.f, 0.f, 0.f}, p1 = {0.f, 0.f, 0.f, 0.f};
  if (hasprev) {
    const float4* pr = (const float4*)(h + (size_t)(row - 1) * H_);
    p0 = pr[tid * 2 + 0]; p1 = pr[tid * 2 + 1];
  }
  float4 red;
  red.x = c0.x + c0.y + c0.z + c0.w + c1.x + c1.y + c1.z + c1.w;
  red.y = c0.x * c0.x + c0.y * c0.y + c0.z * c0.z + c0.w * c0.w +
          c1.x * c1.x + c1.y * c1.y + c1.z * c1.z + c1.w * c1.w;
  red.z = p0.x + p0.y + p0.z + p0.w + p1.x + p1.y + p1.z + p1.w;
  red.w = p0.x * p0.x + p0.y * p0.y + p0.z * p0.z + p0.w * p0.w +
          p1.x * p1.x + p1.y * p1.y + p1.z * p1.z + p1.w * p1.w;
  #pragma unroll
  for (int off = 32; off; off >>= 1) {
    red.x += __shfl_down(red.x, off);
    red.y += __shfl_down(red.y, off);
    red.z += __shfl_down(red.z, off);
    red.w += __shfl_down(red.w, off);
  }
  __shared__ float4 rbuf_[4];
  const int lane = tid & 63, wid = tid >> 6;
  if (lane == 0) rbuf_[wid] = red;
  __syncthreads();
  float4 tot;
  tot.x = rbuf_[0].x + rbuf_[1].x + rbuf_[2].x + rbuf_[3].x;
  tot.y = rbuf_[0].y + rbuf_[1].y + rbuf_[2].y + rbuf_[3].y;
  tot.z = rbuf_[0].z + rbuf_[1].z + rbuf_[2].z + rbuf_[3].z;
  tot.w = rbuf_[0].w + rbuf_[1].w + rbuf_[2].w + rbuf_[3].w;

  const float inv = 1.0f / (float)H_;
  float mu = tot.x * inv;
  float rstd = rsqrtf(fmaxf(tot.y * inv - mu * mu, 0.f) + 1e-5f);
  float mup = tot.z * inv;
  float rstdp = rsqrtf(fmaxf(tot.w * inv - mup * mup, 0.f) + 1e-5f);

  float xc[8] = {c0.x, c0.y, c0.z, c0.w, c1.x, c1.y, c1.z, c1.w};
  float xp[8] = {p0.x, p0.y, p0.z, p0.w, p1.x, p1.y, p1.z, p1.w};
  const float4* W4 = (const float4*)lnw;
  const float4* Bv4 = (const float4*)lnb;
  const float4* MK4 = (const float4*)mk;
  const float4* MV4 = (const float4*)mv;
  const float4* MR4 = (const float4*)mr;
  float4 w0 = W4[tid * 2], w1 = W4[tid * 2 + 1];
  float4 b0 = Bv4[tid * 2], b1 = Bv4[tid * 2 + 1];
  float4 k0 = MK4[tid * 2], k1 = MK4[tid * 2 + 1];
  float4 v0 = MV4[tid * 2], v1 = MV4[tid * 2 + 1];
  float4 r0 = MR4[tid * 2], r1 = MR4[tid * 2 + 1];
  float wa[8] = {w0.x, w0.y, w0.z, w0.w, w1.x, w1.y, w1.z, w1.w};
  float ba[8] = {b0.x, b0.y, b0.z, b0.w, b1.x, b1.y, b1.z, b1.w};
  float ka[8] = {k0.x, k0.y, k0.z, k0.w, k1.x, k1.y, k1.z, k1.w};
  float va[8] = {v0.x, v0.y, v0.z, v0.w, v1.x, v1.y, v1.z, v1.w};
  float ra[8] = {r0.x, r0.y, r0.z, r0.w, r1.x, r1.y, r1.z, r1.w};

  bf16x8 ok_, ov_, or_;
  float xls[8];
  #pragma unroll
  for (int e = 0; e < 8; e++) {
    float x = (xc[e] - mu) * rstd * wa[e] + ba[e];
    float sx = hasprev ? (xp[e] - mup) * rstdp * wa[e] + ba[e] : 0.f;
    ok_[e] = (__bf16)(sx + ka[e] * (x - sx));
    ov_[e] = (__bf16)(sx + va[e] * (x - sx));
    or_[e] = (__bf16)(sx + ra[e] * (x - sx));
    xls[e] = x;
  }
  size_t obase = (size_t)row * H_ + tid * 8;
  *(bf16x8*)(xk + obase) = ok_;
  *(bf16x8*)(xv + obase) = ov_;
  *(bf16x8*)(xr + obase) = or_;
  if (t == T_ - 1) {
    float* dst = xlast + (size_t)(row >> 11) * H_ + tid * 8;
    #pragma unroll
    for (int e = 0; e < 8; e++) dst[e] = xls[e];
  }
}

// ----------------------- fused k/v/r bf16 NT GEMM, 128^2 tile, BK=64
// R10 map (per-z XCD swizzle, bm-first chunk) + R12 setprio (T5).
// Verified: ~197 us for 3 GEMM-equivalents, MfmaUtil 48%.
__global__ __launch_bounds__(256, 2) void gemm_kvr(
    const __bf16* __restrict__ A0, const __bf16* __restrict__ A1,
    const __bf16* __restrict__ A2, const __bf16* __restrict__ Wb,
    __bf16* __restrict__ o0, __bf16* __restrict__ o1, __bf16* __restrict__ o2) {
  __shared__ __align__(16) char ring[2][32768];   // [buf][A 16K | B 16K]

  // z-slab, then per-z bijective XCD swizzle with bm-first chunk order.
  const int wgid = blockIdx.x;          // 0..3071
  const int z = wgid >> 10;             // 0..2
  const int g = wgid & 1023;
  const int x = g & 7;                  // XCD
  const int i = g >> 3;                 // 0..127 within XCD chunk
  const int bm = x * 8 + (i & 7);       // 0..63  (M/128), bm-first
  const int bn = i >> 3;                // 0..15  (N/128)

  const __bf16* A = (z == 0) ? A0 : (z == 1 ? A1 : A2);
  const __bf16* Bw = Wb + (size_t)z * H_ * H_;
  __bf16* ob = (z == 0) ? o0 : (z == 1 ? o1 : o2);

  const int tid = threadIdx.x;
  const int lane = tid & 63, wv = tid >> 6;   // 4 waves
  const int wm = wv >> 1;           // 0..1
  const int wn = wv & 1;            // 0..1
  const int rr = lane & 15, q = lane >> 4;

  f32x4 acc[4][4];
  #pragma unroll
  for (int m = 0; m < 4; m++)
    #pragma unroll
    for (int n = 0; n < 4; n++) acc[m][n] = (f32x4){0.f, 0.f, 0.f, 0.f};

  const char* Ag = (const char*)A + (size_t)(bm * 128) * (H_ * 2);
  const char* Bg = (const char*)Bw + (size_t)(bn * 128) * (H_ * 2);

  const int srow = wv * 8 + (lane >> 3);            // 0..31 within round
  const int scol = ((lane & 7) ^ (lane >> 3)) << 4; // inverse swizzle
  const int rsw = rr & 7;                            // ds_read swizzle

#define STAGE_TILE(kt_, buf_)                                                   \
  {                                                                             \
    char* base_ = ring[buf_];                                                   \
    _Pragma("unroll")                                                           \
    for (int mh_ = 0; mh_ < 2; mh_++) {                                         \
      const char* Mg_ = mh_ ? Bg : Ag;                                          \
      _Pragma("unroll")                                                         \
      for (int rd_ = 0; rd_ < 4; rd_++) {                                       \
        char* dst_ = base_ + mh_ * 16384 + rd_ * 4096 + wv * 1024;              \
        const char* src_ = Mg_ + (size_t)(rd_ * 32 + srow) * (H_ * 2)           \
                           + (kt_) * 128 + scol;                                \
        async16(src_, dst_);                                                    \
      }                                                                         \
    }                                                                           \
  }

  STAGE_TILE(0, 0);
  asm volatile("s_waitcnt vmcnt(0)" ::: "memory");
  __builtin_amdgcn_s_barrier();

  for (int kt = 0; kt < NKT_; kt++) {
    const int cur = kt & 1, nxt = cur ^ 1;
    const char* Alds = ring[cur];
    const char* Blds = ring[cur] + 16384;

    if (kt + 1 < NKT_) STAGE_TILE(kt + 1, nxt);

    bf16x8 bfr[4][2];
    #pragma unroll
    for (int ni = 0; ni < 4; ni++)
      #pragma unroll
      for (int ks = 0; ks < 2; ks++) {
        int row_t = wn * 64 + ni * 16 + rr;
        bfr[ni][ks] = *(const bf16x8*)(Blds + row_t * 128 +
                                       (((ks * 4 + q) ^ rsw) << 4));
      }

    __builtin_amdgcn_s_setprio(1);
    #pragma unroll
    for (int mi = 0; mi < 4; mi++) {
      bf16x8 af[2];
      #pragma unroll
      for (int ks = 0; ks < 2; ks++) {
        int row_t = wm * 64 + mi * 16 + rr;
        af[ks] = *(const bf16x8*)(Alds + row_t * 128 +
                                  (((ks * 4 + q) ^ rsw) << 4));
      }
      #pragma unroll
      for (int ks = 0; ks < 2; ks++)
        #pragma unroll
        for (int ni = 0; ni < 4; ni++)
          acc[mi][ni] = __builtin_amdgcn_mfma_f32_16x16x32_bf16(
              af[ks], bfr[ni][ks], acc[mi][ni], 0, 0, 0);
    }
    __builtin_amdgcn_s_setprio(0);

    if (kt + 1 < NKT_) {
      asm volatile("s_waitcnt vmcnt(0)" ::: "memory");
      __builtin_amdgcn_s_barrier();
    }
  }
#undef STAGE_TILE

  const int r0 = bm * 128 + wm * 64 + q * 4;
  const int c0 = bn * 128 + wn * 64 + rr;
  #pragma unroll
  for (int mi = 0; mi < 4; mi++) {
    #pragma unroll
    for (int ni = 0; ni < 4; ni++) {
      int col = c0 + ni * 16;
      #pragma unroll
      for (int rg = 0; rg < 4; rg++) {
        int rowg = r0 + mi * 16 + rg;
        size_t idx = (size_t)rowg * H_ + col;
        float vv = acc[mi][ni][rg];
        if (z == 2) {
          ob[idx] = (__bf16)(1.f / (1.f + __expf(-vv)));
        } else {
          ob[idx] = (__bf16)vv;
        }
      }
    }
  }
}

// ----------------------- Wo bf16 NT GEMM, 256^2 tile (R8 verified, 78 us)
__global__ __launch_bounds__(512, 1) void gemm_wo(
    const __bf16* __restrict__ A, const __bf16* __restrict__ Bw,
    float* __restrict__ outf, const float* __restrict__ resid) {
  __shared__ __align__(16) char ring[2][65536];   // [buf][A 32K | B 32K]

  const int wgid = blockIdx.x;
  const int lin = (wgid & 7) * 32 + (wgid >> 3);
  const int bm = lin >> 3;          // 0..31
  const int bn = lin & 7;           // 0..7

  const int tid = threadIdx.x;
  const int lane = tid & 63, wv = tid >> 6;
  const int wm = wv >> 2;           // 0..1
  const int wn = wv & 3;            // 0..3
  const int rr = lane & 15, q = lane >> 4;

  f32x4 acc[8][4];
  #pragma unroll
  for (int m = 0; m < 8; m++)
    #pragma unroll
    for (int n = 0; n < 4; n++) acc[m][n] = (f32x4){0.f, 0.f, 0.f, 0.f};

  const char* Ag = (const char*)A + (size_t)(bm * 256) * (H_ * 2);
  const char* Bg = (const char*)Bw + (size_t)(bn * 256) * (H_ * 2);

  const int srow = wv * 8 + (lane >> 3);
  const int scol = ((lane & 7) ^ (lane >> 3)) << 4;
  const int rsw = rr & 7;

#define STAGE_TILE(kt_, buf_)                                                   \
  {                                                                             \
    char* base_ = ring[buf_];                                                   \
    _Pragma("unroll")                                                           \
    for (int mh_ = 0; mh_ < 2; mh_++) {                                         \
      const char* Mg_ = mh_ ? Bg : Ag;                                          \
      _Pragma("unroll")                                                         \
      for (int hh_ = 0; hh_ < 2; hh_++) {                                       \
        _Pragma("unroll")                                                       \
        for (int rd_ = 0; rd_ < 2; rd_++) {                                     \
          char* dst_ = base_ + mh_ * 32768 + hh_ * 16384 + rd_ * 8192 + wv * 1024; \
          const char* src_ = Mg_ + (size_t)(hh_ * 128 + rd_ * 64 + srow) * (H_ * 2) \
                             + (kt_) * 128 + scol;                              \
          async16(src_, dst_);                                                  \
        }                                                                       \
      }                                                                         \
    }                                                                           \
  }

  STAGE_TILE(0, 0);
  asm volatile("s_waitcnt vmcnt(0)" ::: "memory");
  __builtin_amdgcn_s_barrier();

  for (int kt = 0; kt < NKT_; kt++) {
    const int cur = kt & 1, nxt = cur ^ 1;
    const char* Alds = ring[cur];
    const char* Blds = ring[cur] + 32768;

    if (kt + 1 < NKT_) STAGE_TILE(kt + 1, nxt);

    bf16x8 bfr[4][2];
    #pragma unroll
    for (int ni = 0; ni < 4; ni++)
      #pragma unroll
      for (int ks = 0; ks < 2; ks++) {
        int row_t = wn * 64 + ni * 16 + rr;
        bfr[ni][ks] = *(const bf16x8*)(Blds + row_t * 128 +
                                       (((ks * 4 + q) ^ rsw) << 4));
      }

    #pragma unroll
    for (int p = 0; p < 4; p++) {
      bf16x8 af[2][2];
      #pragma unroll
      for (int mi = 0; mi < 2; mi++)
        #pragma unroll
        for (int ks = 0; ks < 2; ks++) {
          int row_t = wm * 128 + p * 32 + mi * 16 + rr;
          af[mi][ks] = *(const bf16x8*)(Alds + row_t * 128 +
                                        (((ks * 4 + q) ^ rsw) << 4));
        }
      #pragma unroll
      for (int ks = 0; ks < 2; ks++)
        #pragma unroll
        for (int mi = 0; mi < 2; mi++)
          #pragma unroll
          for (int ni = 0; ni < 4; ni++)
            acc[p * 2 + mi][ni] = __builtin_amdgcn_mfma_f32_16x16x32_bf16(
                af[mi][ks], bfr[ni][ks], acc[p * 2 + mi][ni], 0, 0, 0);
    }

    if (kt + 1 < NKT_) {
      asm volatile("s_waitcnt vmcnt(0)" ::: "memory");
      __builtin_amdgcn_s_barrier();
    }
  }
#undef STAGE_TILE

  const int r0 = bm * 256 + wm * 128 + q * 4;
  const int c0 = bn * 256 + wn * 64 + rr;
  #pragma unroll
  for (int m = 0; m < 8; m++) {
    #pragma unroll
    for (int n = 0; n < 4; n++) {
      int col = c0 + n * 16;
      #pragma unroll
      for (int rg = 0; rg < 4; rg++) {
        int rowg = r0 + m * 16 + rg;
        size_t idx = (size_t)rowg * H_ + col;
        outf[idx] = resid[idx] + acc[m][n][rg];
      }
    }
  }
}

// ------------------------------------------------- WKV chunked scan (2 passes)
// pass1: per (b,h,chunk) chunk-local state from zero.
__global__ __launch_bounds__(256) void wkv_pass1(
    const __bf16* __restrict__ k, const __bf16* __restrict__ v,
    const float* __restrict__ td,
    float* __restrict__ cs_num, float* __restrict__ cs_den,
    float* __restrict__ cs_norm) {
  const int id = blockIdx.x * 256 + threadIdx.x;  // 0..B*H-1
  const int c = blockIdx.y;                       // chunk
  const int b = id >> 11;
  const int hh = id & (H_ - 1);
  const float decay = -__expf(td[hh]);
  float num = 0.f, den = 0.f, norm = -INFINITY;

  const int UN = 16;
  for (int t0 = c * CL_; t0 < (c + 1) * CL_; t0 += UN) {
    float kk[UN], vv[UN];
    size_t base = ((size_t)b * T_ + t0) * H_ + hh;
    #pragma unroll
    for (int i = 0; i < UN; i++) {
      kk[i] = (float)k[base + (size_t)i * H_];
      vv[i] = (float)v[base + (size_t)i * H_];
    }
    #pragma unroll
    for (int i = 0; i < UN; i++) {
      float dpn = decay + norm;
      float nn = fmaxf(dpn, kk[i]);
      float ed = __expf(dpn - nn), ek = __expf(kk[i] - nn);
      num = ed * num + ek * vv[i];
      den = ed * den + ek;
      norm = nn;
    }
  }
  cs_num[c * BH_ + id] = num;
  cs_den[c * BH_ + id] = den;
  cs_norm[c * BH_ + id] = norm;
}

// pass2 (scan fused): recompute the exclusive prefix locally from cs[0..c-1]
// (identical arithmetic to the old separate wkv_scan -> bitwise-same result;
// cs arrays are 3 MB, L2/L3-resident), then replay the chunk writing a=r*wkv.
__global__ __launch_bounds__(256) void wkv_pass2(
    const __bf16* __restrict__ k, const __bf16* __restrict__ v,
    const __bf16* __restrict__ r, const float* __restrict__ td,
    const float* __restrict__ cw,
    const float* __restrict__ cs_num, const float* __restrict__ cs_den,
    const float* __restrict__ cs_norm,
    __bf16* __restrict__ a, float* __restrict__ ndn) {
  const int id = blockIdx.x * 256 + threadIdx.x;  // 0..B*H-1
  const int c = blockIdx.y;
  const int b = id >> 11;
  const int hh = id & (H_ - 1);
  const float decay = -__expf(td[hh]);
  const float cwv = cw[hh];
  const float Lw = decay * (float)CL_;

  // exclusive prefix over chunks 0..c-1 (same loop as old wkv_scan)
  float num = 0.f, den = 0.f, norm = -INFINITY;
  for (int cc = 0; cc < c; cc++) {
    float n_c = cs_num[cc * BH_ + id];
    float d_c = cs_den[cc * BH_ + id];
    float m_c = cs_norm[cc * BH_ + id];
    float sn = norm + Lw;
    float on = fmaxf(sn, m_c);            // m_c always finite
    float ea = __expf(sn - on), eb = __expf(m_c - on);
    num = ea * num + eb * n_c;
    den = ea * den + eb * d_c;
    norm = on;
  }

  const int UN = 16;
  for (int t0 = c * CL_; t0 < (c + 1) * CL_; t0 += UN) {
    float kk[UN], vv[UN], rrv[UN];
    size_t base = ((size_t)b * T_ + t0) * H_ + hh;
    #pragma unroll
    for (int i = 0; i < UN; i++) {
      kk[i] = (float)k[base + (size_t)i * H_];
      vv[i] = (float)v[base + (size_t)i * H_];
      rrv[i] = (float)r[base + (size_t)i * H_];
    }
    #pragma unroll
    for (int i = 0; i < UN; i++) {
      float kt = kk[i], vt = vv[i];
      float ct = cwv + kt;
      float cn = fmaxf(ct, norm);
      float ep = __expf(norm - cn), ec = __expf(ct - cn);
      float o = (ep * num + ec * vt) / (ep * den + ec);
      a[base + (size_t)i * H_] = (__bf16)(rrv[i] * o);
      float dpn = decay + norm;
      float nn = fmaxf(dpn, kt);
      float ed = __expf(dpn - nn), ek = __expf(kt - nn);
      num = ed * num + ek * vt;
      den = ed * den + ek;
      norm = nn;
    }
  }
  if (c == CH_ - 1) {
    ndn[id] = num;
    ndn[BH_ + id] = den;
    ndn[2 * BH_ + id] = norm;
  }
}

// ----------------------------------------------------------------------- host
extern "C" void kernel_launch(void* const* d_in, const int* in_sizes, int n_in,
                              void* d_out, int out_size, void* d_ws, size_t ws_size,
                              hipStream_t stream) {
  const float* h   = (const float*)d_in[0];
  const float* lnw = (const float*)d_in[1];
  const float* lnb = (const float*)d_in[2];
  const float* Wk  = (const float*)d_in[3];
  const float* Wv  = (const float*)d_in[4];
  const float* Wr  = (const float*)d_in[5];
  const float* Wo  = (const float*)d_in[6];
  const float* mk  = (const float*)d_in[7];
  const float* mv  = (const float*)d_in[8];
  const float* mr  = (const float*)d_in[9];
  const float* td  = (const float*)d_in[10];
  const float* cw  = (const float*)d_in[11];

  char* ws = (char*)d_ws;
  const size_t MB = 1048576;
  // Workspace layout (224 MB of 256):
  //   [0,32)    xk   (bf16, later reused as 'a' = r*wkv)
  //   [32,64)   xv   (bf16)
  //   [64,96)   xr   (bf16; dead after fused GEMM -> scan state (3 MB) here)
  //   [96,128)  kbuf (bf16)
  //   [128,160) vbuf (bf16)
  //   [160,192) W16: Wk/Wv/Wr/Wo bf16, 8 MB each (contiguous)
  //   [192,224) rbuf (bf16)
  __bf16* xk   = (__bf16*)(ws);
  __bf16* xv   = (__bf16*)(ws + 32 * MB);
  __bf16* xr   = (__bf16*)(ws + 64 * MB);
  __bf16* kbuf = (__bf16*)(ws + 96 * MB);
  __bf16* vbuf = (__bf16*)(ws + 128 * MB);
  __bf16* W16  = (__bf16*)(ws + 160 * MB);
  __bf16* rbuf = (__bf16*)(ws + 192 * MB);
  __bf16* Wo16 = W16 + 3 * (size_t)H_ * H_;
  float* cs_num  = (float*)(ws + 64 * MB);     // 3 x CH_*BH_ f32 = 3 MB
  float* cs_den  = cs_num + (size_t)CH_ * BH_;
  float* cs_norm = cs_den + (size_t)CH_ * BH_;

  float* out  = (float*)d_out;
  float* xlast = out + (size_t)BT_ * H_;
  float* ndn   = xlast + (size_t)B_ * H_;

  dim3 cg((H_ * H_) / (256 * 8), 4);
  cvt_bf16_kernel<<<cg, 256, 0, stream>>>(Wk, Wv, Wr, Wo, W16);

  ln_mix_kernel<<<BT_, 256, 0, stream>>>(h, lnw, lnb, mk, mv, mr, xk, xv, xr, xlast);

  // fused k/v/r GEMM: 3 x (64 x 16) blocks, per-z XCD swizzle (R10 map) + T5
  gemm_kvr<<<3072, 256, 0, stream>>>(xk, xv, xr, W16, kbuf, vbuf, rbuf);

  dim3 wg(BH_ / 256, CH_);
  wkv_pass1<<<wg, 256, 0, stream>>>(kbuf, vbuf, td, cs_num, cs_den, cs_norm);
  wkv_pass2<<<wg, 256, 0, stream>>>(kbuf, vbuf, rbuf, td, cw,
                                    cs_num, cs_den, cs_norm,
                                    xk /* a reuses xk */, ndn);

  // Wo GEMM + residual at 256^2 (R8-verified fast variant)
  gemm_wo<<<256, 512, 0, stream>>>(xk, Wo16, out, h);
}